// Round 1
// baseline (415.237 us; speedup 1.0000x reference)
//
#include <hip/hip_runtime.h>

#define BATCH 4096
#define NB    64
#define DM    256
#define PITCH 264   // bf16 elems per LDS row: 256 + 8 pad -> row stride 528 B (132 dwords, %32==4)

typedef __bf16 bf16x8 __attribute__((ext_vector_type(8)));
typedef float  f32x4  __attribute__((ext_vector_type(4)));

union Frag16 { uint4 u; bf16x8 b; ushort s[8]; };

__device__ __forceinline__ ushort f2bf(float x) {
    unsigned u = __float_as_uint(x);
    unsigned r = (u + 0x7FFFu + ((u >> 16) & 1u)) >> 16;   // RNE, inputs finite
    return (ushort)r;
}
__device__ __forceinline__ float bf2f(ushort u) {
    return __uint_as_float(((unsigned)u) << 16);
}

// ---- pre-pass: swizzle W (fp32 [256][256], row-major [k][e]) into bf16 B-fragment order ----
// Wf[(et*8 + ks)*64 + lane] (16 B) = { W[ks*32 + (lane>>4)*8 + j][et*16 + (lane&15)] : j=0..7 }
__global__ void swizzle_W(const float* __restrict__ W, ushort* __restrict__ Wf) {
    int idx  = blockIdx.x * 256 + threadIdx.x;   // 0..8191
    int lane = idx & 63;
    int ks   = (idx >> 6) & 7;
    int et   = idx >> 9;                          // 0..15
    int e    = et * 16 + (lane & 15);
    int k0   = ks * 32 + ((lane >> 4) << 3);
    Frag16 f;
#pragma unroll
    for (int j = 0; j < 8; ++j)
        f.s[j] = f2bf(W[(k0 + j) * DM + e]);
    reinterpret_cast<uint4*>(Wf)[idx] = f.u;
}

// ---- fused: S = tanh(H W + ba); a = softmax(S, axis=n); out[n] = sum_e a[n,e]*h[n,e] ----
__global__ __launch_bounds__(256) void aspect_attn(
    const float*  __restrict__ h,
    const ushort* __restrict__ Wf,
    const float*  __restrict__ ba,
    float*        __restrict__ out)
{
    __shared__ __align__(16) ushort Hs[NB * PITCH];   // 33792 B
    __shared__ float op[4][NB];                       // 1 KB cross-wave reduce

    const int tid  = threadIdx.x;
    const int wave = tid >> 6;
    const int lane = tid & 63;
    const int quad = lane >> 4;
    const int l15  = lane & 15;
    const int b    = blockIdx.x;

    const float* hb = h + (size_t)b * (NB * DM);

    // ---- stage H tile (64x256 fp32 -> bf16 LDS), coalesced float4 loads ----
#pragma unroll
    for (int it = 0; it < 16; ++it) {
        int g   = it * 256 + tid;        // float4 group 0..4095
        int row = g >> 6;                // 64 float4 groups per row
        int c   = (g & 63) << 2;
        f32x4 v = reinterpret_cast<const f32x4*>(hb)[g];
        ushort4 o;
        o.x = f2bf(v.x); o.y = f2bf(v.y); o.z = f2bf(v.z); o.w = f2bf(v.w);
        *reinterpret_cast<ushort4*>(&Hs[row * PITCH + c]) = o;
    }
    __syncthreads();

    // ---- GEMM: wave w computes S[0:64][64w : 64w+64] ----
    f32x4 acc[4][4];
#pragma unroll
    for (int mt = 0; mt < 4; ++mt)
#pragma unroll
        for (int nt = 0; nt < 4; ++nt) {
            f32x4 z = {0.f, 0.f, 0.f, 0.f};
            acc[mt][nt] = z;
        }

    const uint4* WfB = reinterpret_cast<const uint4*>(Wf);
#pragma unroll
    for (int ks = 0; ks < 8; ++ks) {
        Frag16 af[4], bfr[4];
#pragma unroll
        for (int mt = 0; mt < 4; ++mt) {
            int row = mt * 16 + l15;
            af[mt].u = *reinterpret_cast<const uint4*>(&Hs[row * PITCH + ks * 32 + quad * 8]);
        }
#pragma unroll
        for (int nt = 0; nt < 4; ++nt)
            bfr[nt].u = WfB[(((wave * 4 + nt) * 8) + ks) * 64 + lane];
#pragma unroll
        for (int mt = 0; mt < 4; ++mt)
#pragma unroll
            for (int nt = 0; nt < 4; ++nt)
                acc[mt][nt] = __builtin_amdgcn_mfma_f32_16x16x32_bf16(
                    af[mt].b, bfr[nt].b, acc[mt][nt], 0, 0, 0);
    }

    const int colbase = wave * 64;

    // ---- bias + tanh (bounded output => no softmax max-shift needed) ----
#pragma unroll
    for (int mt = 0; mt < 4; ++mt)
#pragma unroll
        for (int r = 0; r < 4; ++r) {
            int row = mt * 16 + quad * 4 + r;
#pragma unroll
            for (int nt = 0; nt < 4; ++nt) {
                int col = colbase + nt * 16 + l15;
                float x = acc[mt][nt][r] + ba[row * DM + col];
                float e = __expf(-2.f * fabsf(x));
                float t = (1.f - e) * __builtin_amdgcn_rcpf(1.f + e);
                acc[mt][nt][r] = copysignf(t, x);
            }
        }

    // ---- softmax over n (64 rows of a column live across the 4 quads) ----
#pragma unroll
    for (int nt = 0; nt < 4; ++nt) {
        float ls = 0.f;
#pragma unroll
        for (int mt = 0; mt < 4; ++mt)
#pragma unroll
            for (int r = 0; r < 4; ++r) {
                float p = __expf(acc[mt][nt][r]);   // s in (-1,1): safe
                acc[mt][nt][r] = p;
                ls += p;
            }
        ls += __shfl_xor(ls, 16, 64);
        ls += __shfl_xor(ls, 32, 64);
        float inv = __builtin_amdgcn_rcpf(ls);
#pragma unroll
        for (int mt = 0; mt < 4; ++mt)
#pragma unroll
            for (int r = 0; r < 4; ++r)
                acc[mt][nt][r] *= inv;
    }

    // ---- out[n] = sum_e a[n,e] * h[n,e]: lane sums its 4 cols, xor-reduce 16 lanes ----
#pragma unroll
    for (int mt = 0; mt < 4; ++mt)
#pragma unroll
        for (int r = 0; r < 4; ++r) {
            int row = mt * 16 + quad * 4 + r;
            float s = 0.f;
#pragma unroll
            for (int nt = 0; nt < 4; ++nt) {
                int col = colbase + nt * 16 + l15;
                s += acc[mt][nt][r] * bf2f(Hs[row * PITCH + col]);
            }
#pragma unroll
            for (int m = 1; m < 16; m <<= 1)
                s += __shfl_xor(s, m, 64);
            if (l15 == 0) op[wave][row] = s;
        }
    __syncthreads();

    if (tid < NB)
        out[(size_t)b * NB + tid] = op[0][tid] + op[1][tid] + op[2][tid] + op[3][tid];
}

extern "C" void kernel_launch(void* const* d_in, const int* in_sizes, int n_in,
                              void* d_out, int out_size, void* d_ws, size_t ws_size,
                              hipStream_t stream) {
    const float* h  = (const float*)d_in[0];   // [4096, 64, 256] fp32
    const float* W  = (const float*)d_in[1];   // [256, 256] fp32
    const float* ba = (const float*)d_in[2];   // [64, 256] fp32
    float* out = (float*)d_out;                // [4096, 64] fp32
    ushort* Wf = (ushort*)d_ws;                // 128 KB swizzled bf16 W

    swizzle_W<<<32, 256, 0, stream>>>(W, Wf);
    aspect_attn<<<BATCH, 256, 0, stream>>>(h, Wf, ba, out);
}

// Round 2
// 406.845 us; speedup vs baseline: 1.0206x; 1.0206x over previous
//
#include <hip/hip_runtime.h>
#include <hip/hip_bf16.h>

#define BATCH 4096
#define NB    64
#define DM    256
#define KSW   8      // k-steps of W (256/32)
#define KST   10     // total k-steps incl. 2 bias-identity steps (K=320)

typedef __bf16 bf16x8 __attribute__((ext_vector_type(8)));
typedef float  f32x4  __attribute__((ext_vector_type(4)));

union Frag16 { uint4 u; bf16x8 b; ushort s[8]; };
union Pk2    { __hip_bfloat162 v; unsigned u; };

__device__ __forceinline__ ushort f2bf(float x) {
    unsigned u = __float_as_uint(x);
    return (ushort)((u + 0x7FFFu + ((u >> 16) & 1u)) >> 16);   // RNE, finite inputs
}
__device__ __forceinline__ unsigned pk2(float a, float b) {
    Pk2 p; p.v = __float22bfloat162_rn(make_float2(a, b));     // v_cvt_pk_bf16_f32 on gfx950
    return p.u;
}
__device__ __forceinline__ float bf2f(ushort u) {
    return __uint_as_float(((unsigned)u) << 16);
}

// ---- pre-pass: swizzle [W ; ba] (K=320) into bf16 B-fragment order ----
// Wf frag idx = (et*10 + ks)*64 + lane ; et = e-tile (0..15), ks = k-step (0..9)
// frag.s[j] = B'[ks*32 + (lane>>4)*8 + j][et*16 + (lane&15)], rows 256..319 = ba
__global__ void swizzle_WB(const float* __restrict__ W, const float* __restrict__ ba,
                           ushort* __restrict__ Wf) {
    int idx  = blockIdx.x * 256 + threadIdx.x;   // 0..10239
    int lane = idx & 63;
    int g    = idx >> 6;                         // 0..159
    int et   = g / KST;
    int ks   = g % KST;
    int e    = et * 16 + (lane & 15);
    int r0   = (ks < KSW) ? ks * 32 : (ks - KSW) * 32;
    r0 += ((lane >> 4) << 3);
    const float* src = (ks < KSW) ? W : ba;
    Frag16 f;
#pragma unroll
    for (int j = 0; j < 8; ++j)
        f.s[j] = f2bf(src[(r0 + j) * DM + e]);
    reinterpret_cast<uint4*>(Wf)[idx] = f.u;
}

// ---- fused: S = tanh([H|I][W;ba]); a = softmax(S, axis=n); out[n] = sum_e a*h ----
__global__ __launch_bounds__(256, 4) void aspect_attn(
    const float*  __restrict__ h,
    const ushort* __restrict__ Wf,
    float*        __restrict__ out)
{
    // H tile in A-fragment order: slot = (mt*8+ks)*64 + lane, 16 B each -> 32768 B
    __shared__ __align__(16) ushort Hs[2048 * 8];
    __shared__ float op[4][NB];

    const int tid  = threadIdx.x;
    const int wave = tid >> 6;
    const int lane = tid & 63;
    const int quad = lane >> 4;
    const int l15  = lane & 15;
    const int b    = blockIdx.x;

    const float* hb = h + (size_t)b * (NB * DM);

    // ---- stage H: 8 iters, thread loads 32 B (one fragment) and writes one b128 ----
#pragma unroll
    for (int it = 0; it < 8; ++it) {
        int slot = it * 256 + tid;                 // 0..2047
        int f    = slot >> 6;                      // frag idx = mt*8+ks
        int row  = ((f >> 3) << 4) | l15;
        int k0   = ((f & 7) << 5) | (quad << 3);
        const f32x4* p = reinterpret_cast<const f32x4*>(hb + row * DM + k0);
        f32x4 a = p[0], c = p[1];
        uint4 o;
        o.x = pk2(a.x, a.y); o.y = pk2(a.z, a.w);
        o.z = pk2(c.x, c.y); o.w = pk2(c.z, c.w);
        reinterpret_cast<uint4*>(Hs)[slot] = o;
    }
    __syncthreads();

    // ---- GEMM: wave w computes S[0:64][64w : 64w+64], K=320 ----
    f32x4 acc[4][4];
#pragma unroll
    for (int mt = 0; mt < 4; ++mt)
#pragma unroll
        for (int nt = 0; nt < 4; ++nt) {
            f32x4 z = {0.f, 0.f, 0.f, 0.f};
            acc[mt][nt] = z;
        }

    const uint4* WfB = reinterpret_cast<const uint4*>(Wf);
    const uint4* HsB = reinterpret_cast<const uint4*>(Hs);

#pragma unroll
    for (int ks = 0; ks < KSW; ++ks) {
        Frag16 af[4], bfr[4];
#pragma unroll
        for (int mt = 0; mt < 4; ++mt)
            af[mt].u = HsB[(mt * 8 + ks) * 64 + lane];
#pragma unroll
        for (int nt = 0; nt < 4; ++nt)
            bfr[nt].u = WfB[((wave * 4 + nt) * KST + ks) * 64 + lane];
#pragma unroll
        for (int mt = 0; mt < 4; ++mt)
#pragma unroll
            for (int nt = 0; nt < 4; ++nt)
                acc[mt][nt] = __builtin_amdgcn_mfma_f32_16x16x32_bf16(
                    af[mt].b, bfr[nt].b, acc[mt][nt], 0, 0, 0);
    }
    // bias fold: 2 extra k-steps with identity A-fragments (registers only)
#pragma unroll
    for (int kx = 0; kx < 2; ++kx) {
        Frag16 af[4], bfr[4];
#pragma unroll
        for (int nt = 0; nt < 4; ++nt)
            bfr[nt].u = WfB[((wave * 4 + nt) * KST + KSW + kx) * 64 + lane];
        const int kb = kx * 32 + quad * 8;
#pragma unroll
        for (int mt = 0; mt < 4; ++mt) {
            int d = (mt * 16 + l15) - kb;          // one-hot position, if in [0,8)
#pragma unroll
            for (int j = 0; j < 8; ++j)
                af[mt].s[j] = (d == j) ? (ushort)0x3F80 : (ushort)0;
        }
#pragma unroll
        for (int mt = 0; mt < 4; ++mt)
#pragma unroll
            for (int nt = 0; nt < 4; ++nt)
                acc[mt][nt] = __builtin_amdgcn_mfma_f32_16x16x32_bf16(
                    af[mt].b, bfr[nt].b, acc[mt][nt], 0, 0, 0);
    }

    // ---- tanh (bounded => softmax needs no max-shift) ----
#pragma unroll
    for (int mt = 0; mt < 4; ++mt)
#pragma unroll
        for (int nt = 0; nt < 4; ++nt)
#pragma unroll
            for (int r = 0; r < 4; ++r) {
                float x = acc[mt][nt][r];
                float e = __expf(-2.f * fabsf(x));
                float t = (1.f - e) * __builtin_amdgcn_rcpf(1.f + e);
                acc[mt][nt][r] = copysignf(t, x);
            }

    // ---- softmax over n (column's 64 rows live across the 4 quads) ----
#pragma unroll
    for (int nt = 0; nt < 4; ++nt) {
        float ls = 0.f;
#pragma unroll
        for (int mt = 0; mt < 4; ++mt)
#pragma unroll
            for (int r = 0; r < 4; ++r) {
                float p = __expf(acc[mt][nt][r]);   // s in (-1,1): safe
                acc[mt][nt][r] = p;
                ls += p;
            }
        ls += __shfl_xor(ls, 16, 64);
        ls += __shfl_xor(ls, 32, 64);
        float inv = __builtin_amdgcn_rcpf(ls);
#pragma unroll
        for (int mt = 0; mt < 4; ++mt)
#pragma unroll
            for (int r = 0; r < 4; ++r)
                acc[mt][nt][r] *= inv;
    }

    // ---- out[n] = sum_e a[n,e]*h[n,e]; h re-read from frag-order LDS ----
    const int colb = wave * 64;
#pragma unroll
    for (int mt = 0; mt < 4; ++mt)
#pragma unroll
        for (int r = 0; r < 4; ++r) {
            const int row  = mt * 16 + quad * 4 + r;
            const int ridx = mt * 4096 + (quad * 4 + r) * 8;   // frag-layout row part
            float s = 0.f;
#pragma unroll
            for (int nt = 0; nt < 4; ++nt) {
                int col  = colb + nt * 16 + l15;
                int coff = (col >> 5) * 512 + ((col >> 3) & 3) * 128 + (col & 7);
                s += acc[mt][nt][r] * bf2f(Hs[ridx + coff]);
            }
#pragma unroll
            for (int m = 1; m < 16; m <<= 1)
                s += __shfl_xor(s, m, 64);
            if (l15 == 0) op[wave][row] = s;
        }
    __syncthreads();

    if (tid < NB)
        out[(size_t)b * NB + tid] = op[0][tid] + op[1][tid] + op[2][tid] + op[3][tid];
}

extern "C" void kernel_launch(void* const* d_in, const int* in_sizes, int n_in,
                              void* d_out, int out_size, void* d_ws, size_t ws_size,
                              hipStream_t stream) {
    const float* h  = (const float*)d_in[0];   // [4096, 64, 256] fp32
    const float* W  = (const float*)d_in[1];   // [256, 256] fp32
    const float* ba = (const float*)d_in[2];   // [64, 256] fp32
    float* out = (float*)d_out;                // [4096, 64] fp32
    ushort* Wf = (ushort*)d_ws;                // 160 KB swizzled bf16 [W ; ba]

    swizzle_WB<<<40, 256, 0, stream>>>(W, ba, Wf);
    aspect_attn<<<BATCH, 256, 0, stream>>>(h, Wf, out);
}